// Round 5
// baseline (556.326 us; speedup 1.0000x reference)
//
#include <hip/hip_runtime.h>
#include <math.h>

namespace {
constexpr int B_ = 4;
constexpr int N_ = 2048;
constexpr int K_ = 48;
constexpr int MAX_REL_ = 32;
constexpr int EDGE_C_ = 128;
constexpr int PE_IN_ = 66;    // 2*MAX_REL + 2
constexpr int NUM_PE_ = 16;
constexpr int NROWS = B_ * N_;      // 8192
constexpr int NEDGE = NROWS * K_;   // 393216
}

// ---------------- kernel 1: X = coords[center] * mask ----------------
__global__ __launch_bounds__(256) void x_kernel(const float* __restrict__ coords,
                                                const float* __restrict__ mask,
                                                const int* __restrict__ t2ca,
                                                float* __restrict__ X) {
    int r = blockIdx.x * 256 + threadIdx.x;
    if (r >= NROWS) return;
    int b = r >> 11;                 // N_ = 2048
    int c = t2ca[r];
    float m = mask[r];
    const float* s = coords + ((size_t)(b * N_ + c)) * 3;
    X[r * 3 + 0] = __fmul_rn(s[0], m);
    X[r * 3 + 1] = __fmul_rn(s[1], m);
    X[r * 3 + 2] = __fmul_rn(s[2], m);
}

// ---------------- kernel 2: masked distances + stable top-K (smallest) --------
// One wave (64 lanes) per row; 4 rows per 256-thread block.
// f32 keys, clang -ffp-contract=on chain (LHS-fmul fusion):
//   d2 = fma(dz,dz, fma(dx,dx, dy*dy));  d = m2 * sqrt(d2 + 1e-6)
// Ties (exact-equal keys): LOWER index first (stable top_k semantics).
__global__ __launch_bounds__(256) void knn_kernel(const float* __restrict__ X,
                                                  const float* __restrict__ mask,
                                                  float* __restrict__ eidx_f,
                                                  float* __restrict__ dneb) {
    __shared__ float sdist[4][N_];   // 32 KB
    const int wave = threadIdx.x >> 6;
    const int lane = threadIdx.x & 63;
    const int row = blockIdx.x * 4 + wave;   // grid = NROWS/4, always in range
    const int b = row >> 11;
    float* dist = sdist[wave];

    const float xi0 = X[row * 3 + 0];
    const float xi1 = X[row * 3 + 1];
    const float xi2 = X[row * 3 + 2];
    const float mi = mask[row];
    const float* Xb = X + (size_t)b * N_ * 3;
    const float* mb = mask + b * N_;

    // pass 1: D = m2 * sqrt(fma-chain + 1e-6), row max
    float lmax = -INFINITY;
    #pragma unroll 4
    for (int t = 0; t < N_ / 64; ++t) {
        int j = t * 64 + lane;
        float dx = __fsub_rn(xi0, Xb[j * 3 + 0]);
        float dy = __fsub_rn(xi1, Xb[j * 3 + 1]);
        float dz = __fsub_rn(xi2, Xb[j * 3 + 2]);
        float d2 = __fmaf_rn(dz, dz, __fmaf_rn(dx, dx, __fmul_rn(dy, dy)));
        float m2 = __fmul_rn(mi, mb[j]);
        float d = __fmul_rn(m2, __fsqrt_rn(__fadd_rn(d2, 1e-6f)));
        dist[j] = d;
        lmax = fmaxf(lmax, d);
    }
    #pragma unroll
    for (int off = 32; off; off >>= 1) lmax = fmaxf(lmax, __shfl_xor(lmax, off, 64));

    // pass 2: D_adjust = D + (1-m2)*Dmax; per-lane chunk min (ties: lowest j)
    float cv = INFINITY; int ci = 0x7FFFFFFF;
    #pragma unroll 4
    for (int t = 0; t < N_ / 64; ++t) {
        int j = t * 64 + lane;
        float m2 = __fmul_rn(mi, mb[j]);
        float d = __fadd_rn(dist[j], __fmul_rn(__fsub_rn(1.0f, m2), lmax));
        dist[j] = d;
        if (d < cv) { cv = d; ci = j; }
    }

    // 48 extraction rounds: global lexicographic (val asc, idx asc) min —
    // stable top_k: ascending D, exact ties by lower index.
    float keep_v = 0.0f; int keep_i = 0;
    for (int k = 0; k < K_; ++k) {
        float v = cv; int idx = ci;
        #pragma unroll
        for (int off = 32; off; off >>= 1) {
            float ov = __shfl_xor(v, off, 64);
            int oi = __shfl_xor(idx, off, 64);
            if (ov < v || (ov == v && oi < idx)) { v = ov; idx = oi; }
        }
        if ((idx & 63) == lane) {          // owner removes + rescans its chunk
            dist[idx] = INFINITY;
            float nv = INFINITY; int ni = 0x7FFFFFFF;
            #pragma unroll 8
            for (int t = 0; t < N_ / 64; ++t) {
                int j = t * 64 + lane;
                float d = dist[j];
                if (d < nv) { nv = d; ni = j; }
            }
            cv = nv; ci = ni;
        }
        if (lane == k) { keep_v = v; keep_i = idx; }
    }
    if (lane < K_) {
        dneb[(size_t)row * K_ + lane] = keep_v;
        eidx_f[(size_t)row * K_ + lane] = (float)keep_i;   // exact int-in-float
    }
}

// ---------------- kernel 3: features -> 33x128 matmul -> LayerNorm ----------
// One wave per edge; each lane owns channels (2*lane, 2*lane+1).
// edge_w columns live in registers (loaded once); pe table in LDS.
__global__ __launch_bounds__(256) void edge_kernel(const float* __restrict__ eidx_f,
                                                   const float* __restrict__ dneb,
                                                   const float* __restrict__ token_bonds,
                                                   const float* __restrict__ pe_w,
                                                   const float* __restrict__ pe_b,
                                                   const float* __restrict__ edge_w,
                                                   const float* __restrict__ ln_g,
                                                   const float* __restrict__ ln_b,
                                                   const int* __restrict__ res_idx,
                                                   const int* __restrict__ is_lig,
                                                   float* __restrict__ Eout) {
    __shared__ float4 s_pe[PE_IN_ * 4];   // pe_w[d,:] + pe_b, 16 floats per d
    const int tid = threadIdx.x;
    for (int idx = tid; idx < PE_IN_ * NUM_PE_; idx += 256) {
        ((float*)s_pe)[idx] = pe_w[idx] + pe_b[idx & 15];
    }
    __syncthreads();

    const int lane = tid & 63;
    // W columns -> registers (66 VGPRs), constant over the edge loop
    float w0[33], w1[33];
    #pragma unroll
    for (int p = 0; p < 33; ++p) {
        float2 w = ((const float2*)edge_w)[p * 64 + lane];
        w0[p] = w.x; w1[p] = w.y;
    }
    const float g0 = ln_g[2 * lane], g1 = ln_g[2 * lane + 1];
    const float bb0 = ln_b[2 * lane], bb1 = ln_b[2 * lane + 1];

    const int r = lane & 15;
    const float mu_r = 2.0f + (float)r * (20.0f / 15.0f);

    const int gwave = blockIdx.x * 4 + (tid >> 6);
    const int nwaves = gridDim.x * 4;

    for (int e = gwave; e < NEDGE; e += nwaves) {
        const int row = e / K_;          // b*N + i
        const int b = row >> 11;
        const int j = (int)(eidx_f[e] + 0.5f);
        const float D = dneb[e];
        const int jrow = b * N_ + j;
        const int ri = res_idx[row], rj = res_idx[jrow];
        const int li = is_lig[row], lj = is_lig[jrow];
        float tb = token_bonds[(size_t)row * N_ + j];
        tb = (li | lj) ? tb : 0.0f;
        const int doff = min(max(ri - rj + MAX_REL_, 0), 2 * MAX_REL_);

        float f[33];
        float4 q0 = s_pe[doff * 4 + 0], q1 = s_pe[doff * 4 + 1];
        float4 q2 = s_pe[doff * 4 + 2], q3 = s_pe[doff * 4 + 3];
        f[0] = q0.x; f[1] = q0.y; f[2] = q0.z; f[3] = q0.w;
        f[4] = q1.x; f[5] = q1.y; f[6] = q1.z; f[7] = q1.w;
        f[8] = q2.x; f[9] = q2.y; f[10] = q2.z; f[11] = q2.w;
        f[12] = q3.x; f[13] = q3.y; f[14] = q3.z; f[15] = q3.w;

        // RBF: lane computes exp for r = lane&15; distribute within 16-group
        float t = (D - mu_r) * 0.8f;          // /1.25
        float ex = __expf(-t * t);
        #pragma unroll
        for (int rr = 0; rr < 16; ++rr)
            f[16 + rr] = __shfl(ex, (lane & 48) | rr, 64);
        f[32] = tb;

        float ax = 0.0f, ay = 0.0f;
        #pragma unroll
        for (int p = 0; p < 33; ++p) {
            ax = fmaf(f[p], w0[p], ax);
            ay = fmaf(f[p], w1[p], ay);
        }

        // LayerNorm over 128 channels (2 per lane)
        float s = ax + ay, sq = ax * ax + ay * ay;
        #pragma unroll
        for (int off = 32; off; off >>= 1) {
            s  += __shfl_xor(s, off, 64);
            sq += __shfl_xor(sq, off, 64);
        }
        float mu = s * (1.0f / 128.0f);
        float var = sq * (1.0f / 128.0f) - mu * mu;
        float rstd = rsqrtf(var + 1e-5f);
        float ox = (ax - mu) * rstd * g0 + bb0;
        float oy = (ay - mu) * rstd * g1 + bb1;
        ((float2*)Eout)[(size_t)e * 64 + lane] = make_float2(ox, oy);
    }
}

extern "C" void kernel_launch(void* const* d_in, const int* in_sizes, int n_in,
                              void* d_out, int out_size, void* d_ws, size_t ws_size,
                              hipStream_t stream) {
    const float* coords      = (const float*)d_in[0];
    const float* mask        = (const float*)d_in[1];
    const float* token_bonds = (const float*)d_in[2];
    const float* pe_w        = (const float*)d_in[3];
    const float* pe_b        = (const float*)d_in[4];
    const float* edge_w      = (const float*)d_in[5];
    const float* ln_g        = (const float*)d_in[6];
    const float* ln_b        = (const float*)d_in[7];
    const int*   t2ca        = (const int*)d_in[8];
    const int*   res_idx     = (const int*)d_in[9];
    // d_in[10] (asym_id) unused: chain_labels = zeros in the reference
    const int*   is_lig      = (const int*)d_in[11];

    float* out    = (float*)d_out;
    float* Eout   = out;                               // NEDGE * 128
    float* eidx_f = out + (size_t)NEDGE * EDGE_C_;     // NEDGE (ints as floats)
    float* dneb   = eidx_f + NEDGE;                    // NEDGE

    float* X = (float*)d_ws;                           // NROWS*3 floats (96 KB)

    hipLaunchKernelGGL(x_kernel, dim3(NROWS / 256), dim3(256), 0, stream,
                       coords, mask, t2ca, X);
    hipLaunchKernelGGL(knn_kernel, dim3(NROWS / 4), dim3(256), 0, stream,
                       X, mask, eidx_f, dneb);
    hipLaunchKernelGGL(edge_kernel, dim3(3072), dim3(256), 0, stream,
                       eidx_f, dneb, token_bonds, pe_w, pe_b, edge_w,
                       ln_g, ln_b, res_idx, is_lig, Eout);
}